// Round 11
// baseline (26374.710 us; speedup 1.0000x reference)
//
#include <hip/hip_runtime.h>
#include <math.h>

// ---------------- problem constants ----------------
#define TT   4096
#define BB   9
#define NHc  500
#define NHP  512
#define NMc  6
// ---------------- grid roles (workers live on ONE XCD) ----------------
#define NAg  8      // A: 64 h1 rows each, W_in_self in REGISTERS
#define NBg  16     // B: 32 h2 rows each, W_out + W_out_self in REGISTERS
#define NWRK (NAg + NBg + 1)
#define RGD  8      // h ring depth
#define IVR  16     // in_vec ring depth

// ws ints: FA[i]=32*i (i<8); FB[j]=1024+32*j (j<16); FC=3040; TICKET=3104.
#define WS_RH1 4096
#define WS_RH2 (WS_RH1 + RGD*BB*NHP)     // 40960
#define WS_RIV (WS_RH2 + RGD*BB*NHP)     // 77824 (+16*108 -> ~318KB)

// PROVEN transport (R1/R6/R8/R9; R2/R3/R5/R10 falsified all alternatives):
//  - flags: publish = agent-scope atomic fetch_add (MALL RMW);
//           poll    = relaxed agent-scope atomic load + s_sleep backoff.
//  - ring data (XCD-local, R9-validated): plain stores -> per-thread
//    s_waitcnt vmcnt(0) -> barrier -> flag RMW; consumers read with sc0
//    (L1-bypass) loads served by the shared per-XCD L2. No fences.
__device__ __forceinline__ bool waitFlag(const int* p, int tgt){
  if (tgt <= 0) return true;
  long long n = 0;
  while (__hip_atomic_load(p, __ATOMIC_RELAXED, __HIP_MEMORY_SCOPE_AGENT) < tgt){
    __builtin_amdgcn_s_sleep(2);
    if (++n > (1LL<<20)) return false;   // safety: wrong answer instead of hang
  }
  return true;
}
// ring slice (BB*NHP floats = 2304 u64) -> LDS, sc0 = bypass L1, hit shared L2
__device__ __forceinline__ void fetchSlice(float* dstLds, const float* src, int tid){
  const unsigned long long* s64 = (const unsigned long long*)src;
  unsigned long long v0,v1,v2,v3,v4,v5,v6,v7,v8;
  asm volatile("global_load_dwordx2 %0, %1, off sc0" : "=v"(v0) : "v"(&s64[tid        ]));
  asm volatile("global_load_dwordx2 %0, %1, off sc0" : "=v"(v1) : "v"(&s64[tid +  256]));
  asm volatile("global_load_dwordx2 %0, %1, off sc0" : "=v"(v2) : "v"(&s64[tid +  512]));
  asm volatile("global_load_dwordx2 %0, %1, off sc0" : "=v"(v3) : "v"(&s64[tid +  768]));
  asm volatile("global_load_dwordx2 %0, %1, off sc0" : "=v"(v4) : "v"(&s64[tid + 1024]));
  asm volatile("global_load_dwordx2 %0, %1, off sc0" : "=v"(v5) : "v"(&s64[tid + 1280]));
  asm volatile("global_load_dwordx2 %0, %1, off sc0" : "=v"(v6) : "v"(&s64[tid + 1536]));
  asm volatile("global_load_dwordx2 %0, %1, off sc0" : "=v"(v7) : "v"(&s64[tid + 1792]));
  asm volatile("global_load_dwordx2 %0, %1, off sc0" : "=v"(v8) : "v"(&s64[tid + 2048]));
  asm volatile("s_waitcnt vmcnt(0)" ::: "memory");
  __builtin_amdgcn_sched_barrier(0);
  unsigned long long* d64 = (unsigned long long*)dstLds;
  d64[tid       ] = v0; d64[tid +  256] = v1; d64[tid +  512] = v2;
  d64[tid +  768] = v3; d64[tid + 1024] = v4; d64[tid + 1280] = v5;
  d64[tid + 1536] = v6; d64[tid + 1792] = v7; d64[tid + 2048] = v8;
}
__device__ __forceinline__ unsigned long long ld2sc0(const float* src){
  unsigned long long v;
  asm volatile("global_load_dwordx2 %0, %1, off sc0\n\ts_waitcnt vmcnt(0)"
               : "=v"(v) : "v"(src) : "memory");
  return v;
}

extern "C" __global__ void __launch_bounds__(256, 1)
fb_pipe(const float* __restrict__ pert,
        const float* __restrict__ n1g, const float* __restrict__ n2g,
        const float* __restrict__ nmg, const float* __restrict__ homeg,
        const float* __restrict__ Win,  const float* __restrict__ binp,
        const float* __restrict__ Wis,  const float* __restrict__ Wo,
        const float* __restrict__ boutp,const float* __restrict__ Wos,
        const float* __restrict__ Wmus, const float* __restrict__ Marm,
        float* __restrict__ out, float* ws)
{
  __shared__ float sm[8192];           // 32 KB, role-specific layout
  __shared__ unsigned smDead;
  __shared__ int smRank;
  int* FLG = (int*)ws;
  float* RH1 = ws + WS_RH1;
  float* RH2 = ws + WS_RH2;
  float* RIV = ws + WS_RIV;

  const int tid = threadIdx.x;
  const int wave = tid >> 6, lane = tid & 63;
  const int kk = lane & 15, rr = lane >> 4;

  // ---- claim a worker slot iff this block landed on XCD 0 ----
  if (tid == 0){
    unsigned xcc;
    asm volatile("s_getreg_b32 %0, hwreg(HW_REG_XCC_ID)" : "=s"(xcc));
    int r = -1;
    if (xcc == 0)
      r = __hip_atomic_fetch_add(&FLG[3104], 1, __ATOMIC_RELAXED, __HIP_MEMORY_SCOPE_AGENT);
    smRank = r;
    smDead = 0u;
  }
  __syncthreads();
  const int rank = smRank;
  if (rank < 0 || rank >= NWRK) return;

  if (rank < NAg) {
    // ======== stage A : h1 rows [rank*64, +64), weights in registers ========
    float* Xh   = sm;            // [BB][NHP]
    float* ivl  = sm + 4608;     // [BB][12]
    float* WinL = sm + 4716;     // [64][12]
    float* binL = sm + 5484;     // [64]
    float* stg  = sm + 5548;     // [64][9]
    const int rowBase = rank * 64;
    int* myF = &FLG[rank*32];
    const int wr = wave*16 + rr*4;       // 4 rows per thread
    float4 wreg[4][8];
    for (int q = 0; q < 4; ++q){
      int gr = rowBase + wr + q;
      for (int it = 0; it < 8; ++it){
        int jb = it*64 + kk*4;
        float4 v = {0.f,0.f,0.f,0.f};
        if (gr < NHc && jb < NHc) v = *(const float4*)&Wis[gr*NHc + jb];
        wreg[q][it] = v;
      }
    }
    for (int i = tid; i < 64*12; i += 256){
      int r = i/12, c = i%12; int gr = rowBase + r;
      WinL[i] = (gr < NHc) ? Win[gr*12 + c] : 0.f;
    }
    if (tid < 64){ int gr = rowBase + tid; binL[tid] = (gr < NHc) ? binp[gr] : 0.f; }
    __syncthreads();

    for (int s = 0; s < TT; ++s){
      float nz0=0.f, nz1=0.f, nz2=0.f;
      if (s > 0){
        { int i=tid,     b=i>>6, r=i&63, gr=rowBase+r; if (gr<NHc) nz0=n1g[(size_t)(s-1)*4500 + b*500 + gr]; }
        { int i=tid+256, b=i>>6, r=i&63, gr=rowBase+r; if (gr<NHc) nz1=n1g[(size_t)(s-1)*4500 + b*500 + gr]; }
        if (tid < 64){ int i=tid+512, b=i>>6, r=i&63, gr=rowBase+r; if (gr<NHc) nz2=n1g[(size_t)(s-1)*4500 + b*500 + gr]; }
      }
      // polls: wave0 = read gates (A peers + C in_vec); wave1 = B backpressure
      if (!smDead){
        bool ok = true;
        if (wave == 0){
          if (lane < NAg)        ok = waitFlag(&FLG[lane*32], s);
          else if (lane == 10){ int t=(s==0)?0:((s<=6)?1:(s-5)); ok = waitFlag(&FLG[3040], t); }
        } else if (wave == 1 && lane < NBg){
          if (s >= RGD) ok = waitFlag(&FLG[1024 + lane*32], s - (RGD-1));
        }
        if (!ok) smDead = 1u;
      }
      __syncthreads();
      if (s == 0){
        for (int i = tid; i < BB*NHP; i += 256) Xh[i] = 0.f;
        if (tid < 108) ivl[tid] = 0.f;
      } else {
        fetchSlice(Xh, RH1 + ((s-1)&7)*4608, tid);
        if (tid < 54){
          int b = tid/6, k0 = (tid%6)*2;
          unsigned long long v = ld2sc0(RIV + (s&15)*108 + b*12 + k0);
          *(unsigned long long*)&ivl[b*12 + k0] = v;
        }
      }
      __syncthreads();

      float acc[4][9];
      for (int q = 0; q < 4; ++q)
        for (int b = 0; b < 9; ++b) acc[q][b] = 0.f;
      #pragma unroll
      for (int it = 0; it < 8; ++it){
        int jb = it*64 + kk*4;
        #pragma unroll
        for (int b = 0; b < 9; ++b){
          float4 h = *(const float4*)&Xh[b*NHP + jb];
          #pragma unroll
          for (int q = 0; q < 4; ++q)
            acc[q][b] = fmaf(wreg[q][it].x,h.x, fmaf(wreg[q][it].y,h.y,
                        fmaf(wreg[q][it].z,h.z, fmaf(wreg[q][it].w,h.w, acc[q][b]))));
        }
      }
      #pragma unroll
      for (int mk = 1; mk < 16; mk <<= 1)
        #pragma unroll
        for (int q = 0; q < 4; ++q)
          #pragma unroll
          for (int b = 0; b < 9; ++b)
            acc[q][b] += __shfl_xor(acc[q][b], mk, 64);
      if (kk < 9){
        #pragma unroll
        for (int q = 0; q < 4; ++q){
          float v = 0.f;
          #pragma unroll
          for (int b = 0; b < 9; ++b){ if (kk == b) v = acc[q][b]; }
          stg[(wr+q)*9 + kk] = v;
        }
      }
      __syncthreads();

      #pragma unroll
      for (int c = 0; c < 3; ++c){
        int i = tid + c*256;
        if (i < 576){
          int b = i>>6, r = i&63, gr = rowBase + r;
          float h = 0.f;
          if (gr < NHc){
            float pre = stg[r*9 + b] + binL[r];
            #pragma unroll
            for (int cc = 0; cc < 10; ++cc) pre = fmaf(ivl[b*12 + cc], WinL[r*12 + 2 + cc], pre);
            if (s == 0) h = tanhf(pre);
            else {
              float hp = Xh[b*NHP + gr];
              float nz = (c==0)?nz0:((c==1)?nz1:nz2);
              h = 0.5f*tanhf(pre) + 0.5f*hp + nz*hp*hp;
            }
          }
          RH1[(s&7)*4608 + b*NHP + gr] = h;     // plain store -> shared L2
        }
      }
      asm volatile("s_waitcnt vmcnt(0)" ::: "memory");
      __syncthreads();
      if (tid == 0)
        __hip_atomic_fetch_add(myF, 1, __ATOMIC_RELAXED, __HIP_MEMORY_SCOPE_AGENT);
    }
  } else if (rank < NAg + NBg) {
    // ======== stage B : h2 rows [(rank-8)*32, +32), both weights in regs ========
    float* Xh  = sm;             // [BB][NHP] (reused: h2_{s-1} then h1_s)
    float* sv  = sm + 4608;      // [288]
    float* stg = sm + 4896;      // [32][9]
    float* boL = sm + 5184;      // [32]
    const int rowBase = (rank - NAg) * 32;
    int* myF = &FLG[1024 + (rank - NAg)*32];
    const int wr = wave*8 + rr*2;        // 2 rows per thread
    float4 wS[2][8], wO[2][8];
    for (int q = 0; q < 2; ++q){
      int gr = rowBase + wr + q;
      for (int it = 0; it < 8; ++it){
        int jb = it*64 + kk*4;
        float4 vs = {0.f,0.f,0.f,0.f}, vo = vs;
        if (gr < NHc && jb < NHc){
          vs = *(const float4*)&Wos[gr*NHc + jb];
          vo = *(const float4*)&Wo [gr*NHc + jb];
        }
        wS[q][it] = vs; wO[q][it] = vo;
      }
    }
    if (tid < 32){ int gr = rowBase + tid; boL[tid] = (gr < NHc) ? boutp[gr] : 0.f; }
    __syncthreads();

    for (int s = 0; s < TT; ++s){
      float nz0=0.f, nz1=0.f;
      if (s > 0){
        { int i=tid, b=i>>5, r=i&31, gr=rowBase+r; if (gr<NHc) nz0=n2g[(size_t)(s-1)*4500 + b*500 + gr]; }
        if (tid < 32){ int r=tid, gr=rowBase+r; if (gr<NHc) nz1=n2g[(size_t)(s-1)*4500 + 8*500 + gr]; }
      }
      // --- phase 1 gates: B peers h2_{s-1} + C backpressure (A NOT yet needed) ---
      if (!smDead){
        bool ok = true;
        if (wave == 0){
          if (lane < NBg)        ok = waitFlag(&FLG[1024 + lane*32], s);
          else if (lane == 20){ if (s >= RGD) ok = waitFlag(&FLG[3040], s - (RGD-1)); }
        }
        if (!ok) smDead = 1u;
      }
      __syncthreads();
      if (s == 0){
        for (int i = tid; i < BB*NHP; i += 256) Xh[i] = 0.f;
      } else {
        fetchSlice(Xh, RH2 + ((s-1)&7)*4608, tid);
      }
      __syncthreads();
      { int i=tid, b=i>>5, r=i&31, gr=rowBase+r; sv[i] = (gr<NHc) ? Xh[b*NHP+gr] : 0.f; }
      if (tid < 32){ int r=tid, gr=rowBase+r; sv[tid+256] = (gr<NHc) ? Xh[8*NHP+gr] : 0.f; }

      float acc[2][9];
      for (int q = 0; q < 2; ++q)
        for (int b = 0; b < 9; ++b) acc[q][b] = 0.f;
      // self part: W_out_self @ h2_{s-1}  (overlaps A's tail)
      #pragma unroll
      for (int it = 0; it < 8; ++it){
        int jb = it*64 + kk*4;
        #pragma unroll
        for (int b = 0; b < 9; ++b){
          float4 h = *(const float4*)&Xh[b*NHP + jb];
          #pragma unroll
          for (int q = 0; q < 2; ++q)
            acc[q][b] = fmaf(wS[q][it].x,h.x, fmaf(wS[q][it].y,h.y,
                        fmaf(wS[q][it].z,h.z, fmaf(wS[q][it].w,h.w, acc[q][b]))));
        }
      }
      // --- phase 2 gate: h1_s ready (proven MALL poll) ---
      if (!smDead && wave == 0 && lane < NAg){
        if (!waitFlag(&FLG[lane*32], s + 1)) smDead = 1u;
      }
      __syncthreads();
      fetchSlice(Xh, RH1 + (s&7)*4608, tid);
      __syncthreads();
      // out part: W_out @ h1_s
      #pragma unroll
      for (int it = 0; it < 8; ++it){
        int jb = it*64 + kk*4;
        #pragma unroll
        for (int b = 0; b < 9; ++b){
          float4 h = *(const float4*)&Xh[b*NHP + jb];
          #pragma unroll
          for (int q = 0; q < 2; ++q)
            acc[q][b] = fmaf(wO[q][it].x,h.x, fmaf(wO[q][it].y,h.y,
                        fmaf(wO[q][it].z,h.z, fmaf(wO[q][it].w,h.w, acc[q][b]))));
        }
      }
      #pragma unroll
      for (int mk = 1; mk < 16; mk <<= 1)
        #pragma unroll
        for (int q = 0; q < 2; ++q)
          #pragma unroll
          for (int b = 0; b < 9; ++b)
            acc[q][b] += __shfl_xor(acc[q][b], mk, 64);
      if (kk < 9){
        #pragma unroll
        for (int q = 0; q < 2; ++q){
          float v = 0.f;
          #pragma unroll
          for (int b = 0; b < 9; ++b){ if (kk == b) v = acc[q][b]; }
          stg[(wr+q)*9 + kk] = v;
        }
      }
      __syncthreads();

      #pragma unroll
      for (int c = 0; c < 2; ++c){
        int i = tid + c*256;
        if (i < 288){
          int b = i>>5, r = i&31, gr = rowBase + r;
          float h = 0.f;
          if (gr < NHc){
            float pre = stg[r*9 + b] + boL[r];
            if (s == 0) h = tanhf(pre);
            else {
              float hp = sv[i];
              float nz = (c==0)?nz0:nz1;
              h = 0.5f*tanhf(pre) + 0.5f*hp + nz*hp*hp;
            }
          }
          RH2[(s&7)*4608 + b*NHP + gr] = h;     // plain store -> shared L2
        }
      }
      asm volatile("s_waitcnt vmcnt(0)" ::: "memory");
      __syncthreads();
      if (tid == 0)
        __hip_atomic_fetch_add(myF, 1, __ATOMIC_RELAXED, __HIP_MEMORY_SCOPE_AGENT);
    }
  } else {
    // ========== stage C : muscles + joints + output + in_vec (+6 ahead) ==========
    float* WmL  = sm;            // [6][516]
    float* Xh   = sm + 3096;     // [BB][NHP]
    float* stg  = sm + 7704;     // [4][6][9]
    float* mst  = sm + 7920;     // [BB][6]
    float* js   = sm + 7974;     // [BB][4]
    float* MaL  = sm + 8010;     // [6][2]
    float* hoL  = sm + 8022;     // [BB][2]
    int* myF = &FLG[3040];
    for (int i = tid; i < 6*512; i += 256){
      int r = i >> 9, j = i & 511;
      WmL[r*516 + j] = (j < NHc) ? Wmus[r*NHc + j] : 0.f;
    }
    if (tid < 12) MaL[tid] = Marm[tid];
    if (tid < 18) hoL[tid] = homeg[tid];
    __syncthreads();

    for (int s = 0; s < TT; ++s){
      float nz = 0.f, pv = 0.f;
      if (s > 0 && tid < 54){
        int u = tid / 9, b = tid % 9;
        nz = nmg[(size_t)(s-1)*(BB*NMc) + b*NMc + u];
      }
      if (s > 0 && tid < 18) pv = pert[(size_t)(s-1)*(BB*2) + tid];
      if (!smDead){
        bool ok = true;
        if (wave == 0 && lane < NBg) ok = waitFlag(&FLG[1024 + lane*32], s + 1);
        if (!ok) smDead = 1u;
      }
      __syncthreads();
      fetchSlice(Xh, RH2 + (s&7)*4608, tid);
      __syncthreads();
      {
        float a0[9], a1[9];
        for (int b = 0; b < 9; ++b){ a0[b] = 0.f; a1[b] = 0.f; }
        const int r0 = (rr < 3 ? rr : 0) * 2;
        #pragma unroll
        for (int it = 0; it < 2; ++it){
          int jb = wave*128 + it*64 + kk*4;
          float4 w0 = *(const float4*)&WmL[r0*516 + jb];
          float4 w1 = *(const float4*)&WmL[(r0+1)*516 + jb];
          #pragma unroll
          for (int b = 0; b < 9; ++b){
            float4 h = *(const float4*)&Xh[b*NHP + jb];
            a0[b] = fmaf(w0.x,h.x, fmaf(w0.y,h.y, fmaf(w0.z,h.z, fmaf(w0.w,h.w, a0[b]))));
            a1[b] = fmaf(w1.x,h.x, fmaf(w1.y,h.y, fmaf(w1.z,h.z, fmaf(w1.w,h.w, a1[b]))));
          }
        }
        #pragma unroll
        for (int mk = 1; mk < 16; mk <<= 1){
          #pragma unroll
          for (int b = 0; b < 9; ++b){
            a0[b] += __shfl_xor(a0[b], mk, 64);
            a1[b] += __shfl_xor(a1[b], mk, 64);
          }
        }
        if (kk < 9 && rr < 3){
          float v0 = 0.f, v1 = 0.f;
          #pragma unroll
          for (int b = 0; b < 9; ++b){ if (kk == b){ v0 = a0[b]; v1 = a1[b]; } }
          stg[wave*54 + (rr*2)*9   + kk] = v0;
          stg[wave*54 + (rr*2+1)*9 + kk] = v1;
        }
      }
      __syncthreads();
      if (tid < 54){
        int u = tid / 9, b = tid % 9;
        float pre = stg[u*9+b] + stg[54 + u*9+b] + stg[108 + u*9+b] + stg[162 + u*9+b];
        float rel = fmaxf(pre, 0.f);
        float mn;
        if (s == 0) mn = rel;
        else {
          float mp = mst[b*6 + u];
          mn = 0.2f*rel + 0.8f*mp + nz*mp*mp;
        }
        mst[b*6 + u] = mn;
      }
      __syncthreads();
      if (s == 0){
        if (tid < 18){
          int b = tid >> 1, c = tid & 1;
          js[b*4 + c] = hoL[b*2 + c];
          js[b*4 + 2 + c] = 0.f;
          out[b*4 + c] = hoL[b*2 + c];
          out[b*4 + 2 + c] = 0.f;
        }
      } else {
        if (tid < 18){
          int b = tid >> 1, c = tid & 1;
          float tq = 0.f;
          #pragma unroll
          for (int u = 0; u < 6; ++u) tq = fmaf(mst[b*6 + u], MaL[u*2 + c], tq);
          tq += pv;
          float v  = js[b*4 + 2 + c] + 0.01f * tq;
          float pn = js[b*4 + c] + 0.01f * v;
          js[b*4 + c] = pn;
          js[b*4 + 2 + c] = v;
          out[(size_t)s*(BB*4) + b*4 + c]     = pn;
          out[(size_t)s*(BB*4) + b*4 + 2 + c] = v;
        }
      }
      __syncthreads();
      if (tid < BB*12){
        int b = tid / 12, k = tid % 12;
        float val;
        if (k < 2)       val = 2.f * (js[b*4 + k] - hoL[b*2 + k]);
        else if (k < 4)  val = 0.5f * js[b*4 + 2 + (k - 2)];
        else if (k < 10) val = mst[b*6 + (k - 4)];
        else             val = 0.f;
        if (s == 0){
          #pragma unroll
          for (int q = 1; q <= 6; ++q) RIV[q*(BB*12) + tid] = val;
        } else {
          RIV[((s + 6) & (IVR-1))*(BB*12) + tid] = val;
        }
      }
      asm volatile("s_waitcnt vmcnt(0)" ::: "memory");
      __syncthreads();
      if (tid == 0)
        __hip_atomic_fetch_add(myF, 1, __ATOMIC_RELAXED, __HIP_MEMORY_SCOPE_AGENT);
    }
  }
}

extern "C" void kernel_launch(void* const* d_in, const int* in_sizes, int n_in,
                              void* d_out, int out_size, void* d_ws, size_t ws_size,
                              hipStream_t stream) {
  const float* pert = (const float*)d_in[1];
  const float* n1   = (const float*)d_in[2];
  const float* n2   = (const float*)d_in[3];
  const float* nm   = (const float*)d_in[4];
  const float* home = (const float*)d_in[5];
  const float* Win  = (const float*)d_in[6];
  const float* bin  = (const float*)d_in[7];
  const float* Wis  = (const float*)d_in[8];
  const float* Wo   = (const float*)d_in[9];
  const float* bout = (const float*)d_in[10];
  const float* Wos  = (const float*)d_in[11];
  const float* Wmus = (const float*)d_in[12];
  const float* Marm = (const float*)d_in[13];
  (void)in_sizes; (void)n_in; (void)out_size; (void)ws_size; // needs ~318 KB ws

  // reset flags + ticket every launch (flags only ever written at MALL)
  (void)hipMemsetAsync(d_ws, 0, 16384, stream);
  // fill the whole chip so every CU gets one block; workers self-select on XCD0
  hipLaunchKernelGGL(fb_pipe, dim3(256), dim3(256), 0, stream,
                     pert, n1, n2, nm, home, Win, bin, Wis, Wo, bout, Wos,
                     Wmus, Marm, (float*)d_out, (float*)d_ws);
}

// Round 12
// 25967.386 us; speedup vs baseline: 1.0157x; 1.0157x over previous
//
#include <hip/hip_runtime.h>
#include <math.h>

// ---------------- problem constants ----------------
#define TT   4096
#define BB   9
#define NHc  500
#define NHP  512
#define NMc  6
// ---------------- grid roles (workers live on ONE XCD) ----------------
#define NAg  8      // A: 64 h1 rows each, W_in_self in REGISTERS
#define NBg  16     // B: 32 h2 rows each, W_out + W_out_self in REGISTERS
#define NWRK (NAg + NBg + 1)
#define RGD  8      // h ring depth
#define IVR  16     // in_vec ring depth

// ws ints: FA[i]=32*i (i<8); FB[j]=1024+32*j (j<16); FC=3040; TICKET=3104.
#define WS_RH1 4096
#define WS_RH2 (WS_RH1 + RGD*BB*NHP)     // 40960
#define WS_RIV (WS_RH2 + RGD*BB*NHP)     // 77824 (+16*108 -> ~318KB)

// PROVEN transport (R1/R6/R8/R9; R2/R3/R5/R10 falsified all alternatives):
//  - flags: publish = agent-scope atomic fetch_add (MALL RMW);
//           poll    = relaxed agent-scope atomic load (tight, no sleep).
//  - ring data (XCD-local, R9-validated): plain stores -> per-thread
//    s_waitcnt vmcnt(0) -> barrier -> flag RMW; consumers read with sc0
//    (L1-bypass) loads served by the shared per-XCD L2. No fences.
__device__ __forceinline__ bool waitFlag(const int* p, int tgt){
  if (tgt <= 0) return true;
  long long n = 0;
  while (__hip_atomic_load(p, __ATOMIC_RELAXED, __HIP_MEMORY_SCOPE_AGENT) < tgt){
    if (++n > (1LL<<21)) return false;   // safety: wrong answer instead of hang
  }
  return true;
}
// ring slice (BB*NHP floats = 2304 u64) -> LDS, sc0 = bypass L1, hit shared L2
__device__ __forceinline__ void fetchSlice(float* dstLds, const float* src, int tid){
  const unsigned long long* s64 = (const unsigned long long*)src;
  unsigned long long v0,v1,v2,v3,v4,v5,v6,v7,v8;
  asm volatile("global_load_dwordx2 %0, %1, off sc0" : "=v"(v0) : "v"(&s64[tid        ]));
  asm volatile("global_load_dwordx2 %0, %1, off sc0" : "=v"(v1) : "v"(&s64[tid +  256]));
  asm volatile("global_load_dwordx2 %0, %1, off sc0" : "=v"(v2) : "v"(&s64[tid +  512]));
  asm volatile("global_load_dwordx2 %0, %1, off sc0" : "=v"(v3) : "v"(&s64[tid +  768]));
  asm volatile("global_load_dwordx2 %0, %1, off sc0" : "=v"(v4) : "v"(&s64[tid + 1024]));
  asm volatile("global_load_dwordx2 %0, %1, off sc0" : "=v"(v5) : "v"(&s64[tid + 1280]));
  asm volatile("global_load_dwordx2 %0, %1, off sc0" : "=v"(v6) : "v"(&s64[tid + 1536]));
  asm volatile("global_load_dwordx2 %0, %1, off sc0" : "=v"(v7) : "v"(&s64[tid + 1792]));
  asm volatile("global_load_dwordx2 %0, %1, off sc0" : "=v"(v8) : "v"(&s64[tid + 2048]));
  asm volatile("s_waitcnt vmcnt(0)" ::: "memory");
  __builtin_amdgcn_sched_barrier(0);
  unsigned long long* d64 = (unsigned long long*)dstLds;
  d64[tid       ] = v0; d64[tid +  256] = v1; d64[tid +  512] = v2;
  d64[tid +  768] = v3; d64[tid + 1024] = v4; d64[tid + 1280] = v5;
  d64[tid + 1536] = v6; d64[tid + 1792] = v7; d64[tid + 2048] = v8;
}
__device__ __forceinline__ unsigned long long ld2sc0(const float* src){
  unsigned long long v;
  asm volatile("global_load_dwordx2 %0, %1, off sc0\n\ts_waitcnt vmcnt(0)"
               : "=v"(v) : "v"(src) : "memory");
  return v;
}

extern "C" __global__ void __launch_bounds__(256, 1)
fb_pipe(const float* __restrict__ pert,
        const float* __restrict__ n1g, const float* __restrict__ n2g,
        const float* __restrict__ nmg, const float* __restrict__ homeg,
        const float* __restrict__ Win,  const float* __restrict__ binp,
        const float* __restrict__ Wis,  const float* __restrict__ Wo,
        const float* __restrict__ boutp,const float* __restrict__ Wos,
        const float* __restrict__ Wmus, const float* __restrict__ Marm,
        float* __restrict__ out, float* ws)
{
  __shared__ float sm[8192];           // 32 KB, role-specific layout
  __shared__ unsigned smDead;
  __shared__ int smRank;
  int* FLG = (int*)ws;
  float* RH1 = ws + WS_RH1;
  float* RH2 = ws + WS_RH2;
  float* RIV = ws + WS_RIV;

  const int tid = threadIdx.x;
  const int wave = tid >> 6, lane = tid & 63;
  const int kk = lane & 15, rr = lane >> 4;

  // ---- claim a worker slot iff this block landed on XCD 0 ----
  if (tid == 0){
    unsigned xcc;
    asm volatile("s_getreg_b32 %0, hwreg(HW_REG_XCC_ID)" : "=s"(xcc));
    int r = -1;
    if (xcc == 0)
      r = __hip_atomic_fetch_add(&FLG[3104], 1, __ATOMIC_RELAXED, __HIP_MEMORY_SCOPE_AGENT);
    smRank = r;
    smDead = 0u;
  }
  __syncthreads();
  const int rank = smRank;
  if (rank < 0 || rank >= NWRK) return;

  if (rank < NAg) {
    // ======== stage A : h1 rows [rank*64, +64), weights in registers ========
    float* Xh   = sm;            // [BB][NHP]
    float* ivl  = sm + 4608;     // [BB][12]
    float* WinL = sm + 4716;     // [64][12]
    float* binL = sm + 5484;     // [64]
    float* stg  = sm + 5548;     // [64][9]
    const int rowBase = rank * 64;
    int* myF = &FLG[rank*32];
    const int wr = wave*16 + rr*4;       // 4 rows per thread
    float4 wreg[4][8];
    for (int q = 0; q < 4; ++q){
      int gr = rowBase + wr + q;
      for (int it = 0; it < 8; ++it){
        int jb = it*64 + kk*4;
        float4 v = {0.f,0.f,0.f,0.f};
        if (gr < NHc && jb < NHc) v = *(const float4*)&Wis[gr*NHc + jb];
        wreg[q][it] = v;
      }
    }
    for (int i = tid; i < 64*12; i += 256){
      int r = i/12, c = i%12; int gr = rowBase + r;
      WinL[i] = (gr < NHc) ? Win[gr*12 + c] : 0.f;
    }
    if (tid < 64){ int gr = rowBase + tid; binL[tid] = (gr < NHc) ? binp[gr] : 0.f; }
    __syncthreads();

    for (int s = 0; s < TT; ++s){
      float nz0=0.f, nz1=0.f, nz2=0.f;
      if (s > 0){
        { int i=tid,     b=i>>6, r=i&63, gr=rowBase+r; if (gr<NHc) nz0=n1g[(size_t)(s-1)*4500 + b*500 + gr]; }
        { int i=tid+256, b=i>>6, r=i&63, gr=rowBase+r; if (gr<NHc) nz1=n1g[(size_t)(s-1)*4500 + b*500 + gr]; }
        if (tid < 64){ int i=tid+512, b=i>>6, r=i&63, gr=rowBase+r; if (gr<NHc) nz2=n1g[(size_t)(s-1)*4500 + b*500 + gr]; }
      }
      // polls: wave0 = read gates (A peers + C in_vec); wave1 = B backpressure
      if (!smDead){
        bool ok = true;
        if (wave == 0){
          if (lane < NAg)        ok = waitFlag(&FLG[lane*32], s);
          else if (lane == 10){ int t=(s==0)?0:((s<=6)?1:(s-5)); ok = waitFlag(&FLG[3040], t); }
        } else if (wave == 1 && lane < NBg){
          if (s >= RGD) ok = waitFlag(&FLG[1024 + lane*32], s - (RGD-1));
        }
        if (!ok) smDead = 1u;
      }
      __syncthreads();
      if (s == 0){
        for (int i = tid; i < BB*NHP; i += 256) Xh[i] = 0.f;
        if (tid < 108) ivl[tid] = 0.f;
      } else {
        fetchSlice(Xh, RH1 + ((s-1)&7)*4608, tid);
        if (tid < 54){
          int b = tid/6, k0 = (tid%6)*2;
          unsigned long long v = ld2sc0(RIV + (s&15)*108 + b*12 + k0);
          *(unsigned long long*)&ivl[b*12 + k0] = v;
        }
      }
      __syncthreads();

      float acc[4][9];
      for (int q = 0; q < 4; ++q)
        for (int b = 0; b < 9; ++b) acc[q][b] = 0.f;
      #pragma unroll
      for (int it = 0; it < 8; ++it){
        int jb = it*64 + kk*4;
        #pragma unroll
        for (int b = 0; b < 9; ++b){
          float4 h = *(const float4*)&Xh[b*NHP + jb];
          #pragma unroll
          for (int q = 0; q < 4; ++q)
            acc[q][b] = fmaf(wreg[q][it].x,h.x, fmaf(wreg[q][it].y,h.y,
                        fmaf(wreg[q][it].z,h.z, fmaf(wreg[q][it].w,h.w, acc[q][b]))));
        }
      }
      #pragma unroll
      for (int mk = 1; mk < 16; mk <<= 1)
        #pragma unroll
        for (int q = 0; q < 4; ++q)
          #pragma unroll
          for (int b = 0; b < 9; ++b)
            acc[q][b] += __shfl_xor(acc[q][b], mk, 64);
      if (kk < 9){
        #pragma unroll
        for (int q = 0; q < 4; ++q){
          float v = 0.f;
          #pragma unroll
          for (int b = 0; b < 9; ++b){ if (kk == b) v = acc[q][b]; }
          stg[(wr+q)*9 + kk] = v;
        }
      }
      __syncthreads();

      #pragma unroll
      for (int c = 0; c < 3; ++c){
        int i = tid + c*256;
        if (i < 576){
          int b = i>>6, r = i&63, gr = rowBase + r;
          float h = 0.f;
          if (gr < NHc){
            float pre = stg[r*9 + b] + binL[r];
            #pragma unroll
            for (int cc = 0; cc < 10; ++cc) pre = fmaf(ivl[b*12 + cc], WinL[r*12 + 2 + cc], pre);
            if (s == 0) h = tanhf(pre);
            else {
              float hp = Xh[b*NHP + gr];
              float nz = (c==0)?nz0:((c==1)?nz1:nz2);
              h = 0.5f*tanhf(pre) + 0.5f*hp + nz*hp*hp;
            }
          }
          RH1[(s&7)*4608 + b*NHP + gr] = h;     // plain store -> shared L2
        }
      }
      asm volatile("s_waitcnt vmcnt(0)" ::: "memory");
      __syncthreads();
      if (tid == 0)
        __hip_atomic_fetch_add(myF, 1, __ATOMIC_RELAXED, __HIP_MEMORY_SCOPE_AGENT);
    }
  } else if (rank < NAg + NBg) {
    // ======== stage B : h2 rows [(rank-8)*32, +32), OUT-FIRST reorder ========
    // critical h2->h2 cycle = observe(B peers) + fetch h2 + self-mm + epi +
    // publish; the h1 fetch + out-mm run BEFORE the binding wait.
    float* Xh  = sm;             // [BB][NHP] (h1_s first, then h2_{s-1})
    float* sv  = sm + 4608;      // [288]
    float* stg = sm + 4896;      // [32][9]
    float* boL = sm + 5184;      // [32]
    const int rowBase = (rank - NAg) * 32;
    int* myF = &FLG[1024 + (rank - NAg)*32];
    const int wr = wave*8 + rr*2;        // 2 rows per thread
    float4 wS[2][8], wO[2][8];
    for (int q = 0; q < 2; ++q){
      int gr = rowBase + wr + q;
      for (int it = 0; it < 8; ++it){
        int jb = it*64 + kk*4;
        float4 vs = {0.f,0.f,0.f,0.f}, vo = vs;
        if (gr < NHc && jb < NHc){
          vs = *(const float4*)&Wos[gr*NHc + jb];
          vo = *(const float4*)&Wo [gr*NHc + jb];
        }
        wS[q][it] = vs; wO[q][it] = vo;
      }
    }
    if (tid < 32){ int gr = rowBase + tid; boL[tid] = (gr < NHc) ? boutp[gr] : 0.f; }
    __syncthreads();

    for (int s = 0; s < TT; ++s){
      float nz0=0.f, nz1=0.f;
      if (s > 0){
        { int i=tid, b=i>>5, r=i&31, gr=rowBase+r; if (gr<NHc) nz0=n2g[(size_t)(s-1)*4500 + b*500 + gr]; }
        if (tid < 32){ int r=tid, gr=rowBase+r; if (gr<NHc) nz1=n2g[(size_t)(s-1)*4500 + 8*500 + gr]; }
      }
      // --- top gates: A done step s (h1_s ready; A runs ahead) + C backpressure ---
      if (!smDead){
        bool ok = true;
        if (wave == 0){
          if (lane < NAg)        ok = waitFlag(&FLG[lane*32], s + 1);
          else if (lane == 20){ if (s >= RGD) ok = waitFlag(&FLG[3040], s - (RGD-1)); }
        }
        if (!ok) smDead = 1u;
      }
      __syncthreads();
      fetchSlice(Xh, RH1 + (s&7)*4608, tid);      // h1_s
      __syncthreads();

      float acc[2][9];
      for (int q = 0; q < 2; ++q)
        for (int b = 0; b < 9; ++b) acc[q][b] = 0.f;
      // out part FIRST: W_out @ h1_s (runs while peers' h2_{s-1} flags land)
      #pragma unroll
      for (int it = 0; it < 8; ++it){
        int jb = it*64 + kk*4;
        #pragma unroll
        for (int b = 0; b < 9; ++b){
          float4 h = *(const float4*)&Xh[b*NHP + jb];
          #pragma unroll
          for (int q = 0; q < 2; ++q)
            acc[q][b] = fmaf(wO[q][it].x,h.x, fmaf(wO[q][it].y,h.y,
                        fmaf(wO[q][it].z,h.z, fmaf(wO[q][it].w,h.w, acc[q][b]))));
        }
      }
      // --- binding gate: B peers h2_{s-1} ---
      if (s > 0 && !smDead && wave == 0 && lane < NBg){
        if (!waitFlag(&FLG[1024 + lane*32], s)) smDead = 1u;
      }
      __syncthreads();
      if (s == 0){
        for (int i = tid; i < BB*NHP; i += 256) Xh[i] = 0.f;
      } else {
        fetchSlice(Xh, RH2 + ((s-1)&7)*4608, tid);
      }
      __syncthreads();
      { int i=tid, b=i>>5, r=i&31, gr=rowBase+r; sv[i] = (gr<NHc) ? Xh[b*NHP+gr] : 0.f; }
      if (tid < 32){ int r=tid, gr=rowBase+r; sv[tid+256] = (gr<NHc) ? Xh[8*NHP+gr] : 0.f; }
      // self part: W_out_self @ h2_{s-1} (accumulates into same acc)
      #pragma unroll
      for (int it = 0; it < 8; ++it){
        int jb = it*64 + kk*4;
        #pragma unroll
        for (int b = 0; b < 9; ++b){
          float4 h = *(const float4*)&Xh[b*NHP + jb];
          #pragma unroll
          for (int q = 0; q < 2; ++q)
            acc[q][b] = fmaf(wS[q][it].x,h.x, fmaf(wS[q][it].y,h.y,
                        fmaf(wS[q][it].z,h.z, fmaf(wS[q][it].w,h.w, acc[q][b]))));
        }
      }
      #pragma unroll
      for (int mk = 1; mk < 16; mk <<= 1)
        #pragma unroll
        for (int q = 0; q < 2; ++q)
          #pragma unroll
          for (int b = 0; b < 9; ++b)
            acc[q][b] += __shfl_xor(acc[q][b], mk, 64);
      if (kk < 9){
        #pragma unroll
        for (int q = 0; q < 2; ++q){
          float v = 0.f;
          #pragma unroll
          for (int b = 0; b < 9; ++b){ if (kk == b) v = acc[q][b]; }
          stg[(wr+q)*9 + kk] = v;
        }
      }
      __syncthreads();

      #pragma unroll
      for (int c = 0; c < 2; ++c){
        int i = tid + c*256;
        if (i < 288){
          int b = i>>5, r = i&31, gr = rowBase + r;
          float h = 0.f;
          if (gr < NHc){
            float pre = stg[r*9 + b] + boL[r];
            if (s == 0) h = tanhf(pre);
            else {
              float hp = sv[i];
              float nz = (c==0)?nz0:nz1;
              h = 0.5f*tanhf(pre) + 0.5f*hp + nz*hp*hp;
            }
          }
          RH2[(s&7)*4608 + b*NHP + gr] = h;     // plain store -> shared L2
        }
      }
      asm volatile("s_waitcnt vmcnt(0)" ::: "memory");
      __syncthreads();
      if (tid == 0)
        __hip_atomic_fetch_add(myF, 1, __ATOMIC_RELAXED, __HIP_MEMORY_SCOPE_AGENT);
    }
  } else {
    // ========== stage C : muscles + joints + output + in_vec (+6 ahead) ==========
    float* WmL  = sm;            // [6][516]
    float* Xh   = sm + 3096;     // [BB][NHP]
    float* stg  = sm + 7704;     // [4][6][9]
    float* mst  = sm + 7920;     // [BB][6]
    float* js   = sm + 7974;     // [BB][4]
    float* MaL  = sm + 8010;     // [6][2]
    float* hoL  = sm + 8022;     // [BB][2]
    int* myF = &FLG[3040];
    for (int i = tid; i < 6*512; i += 256){
      int r = i >> 9, j = i & 511;
      WmL[r*516 + j] = (j < NHc) ? Wmus[r*NHc + j] : 0.f;
    }
    if (tid < 12) MaL[tid] = Marm[tid];
    if (tid < 18) hoL[tid] = homeg[tid];
    __syncthreads();

    for (int s = 0; s < TT; ++s){
      float nz = 0.f, pv = 0.f;
      if (s > 0 && tid < 54){
        int u = tid / 9, b = tid % 9;
        nz = nmg[(size_t)(s-1)*(BB*NMc) + b*NMc + u];
      }
      if (s > 0 && tid < 18) pv = pert[(size_t)(s-1)*(BB*2) + tid];
      if (!smDead){
        bool ok = true;
        if (wave == 0 && lane < NBg) ok = waitFlag(&FLG[1024 + lane*32], s + 1);
        if (!ok) smDead = 1u;
      }
      __syncthreads();
      fetchSlice(Xh, RH2 + (s&7)*4608, tid);
      __syncthreads();
      {
        float a0[9], a1[9];
        for (int b = 0; b < 9; ++b){ a0[b] = 0.f; a1[b] = 0.f; }
        const int r0 = (rr < 3 ? rr : 0) * 2;
        #pragma unroll
        for (int it = 0; it < 2; ++it){
          int jb = wave*128 + it*64 + kk*4;
          float4 w0 = *(const float4*)&WmL[r0*516 + jb];
          float4 w1 = *(const float4*)&WmL[(r0+1)*516 + jb];
          #pragma unroll
          for (int b = 0; b < 9; ++b){
            float4 h = *(const float4*)&Xh[b*NHP + jb];
            a0[b] = fmaf(w0.x,h.x, fmaf(w0.y,h.y, fmaf(w0.z,h.z, fmaf(w0.w,h.w, a0[b]))));
            a1[b] = fmaf(w1.x,h.x, fmaf(w1.y,h.y, fmaf(w1.z,h.z, fmaf(w1.w,h.w, a1[b]))));
          }
        }
        #pragma unroll
        for (int mk = 1; mk < 16; mk <<= 1){
          #pragma unroll
          for (int b = 0; b < 9; ++b){
            a0[b] += __shfl_xor(a0[b], mk, 64);
            a1[b] += __shfl_xor(a1[b], mk, 64);
          }
        }
        if (kk < 9 && rr < 3){
          float v0 = 0.f, v1 = 0.f;
          #pragma unroll
          for (int b = 0; b < 9; ++b){ if (kk == b){ v0 = a0[b]; v1 = a1[b]; } }
          stg[wave*54 + (rr*2)*9   + kk] = v0;
          stg[wave*54 + (rr*2+1)*9 + kk] = v1;
        }
      }
      __syncthreads();
      if (tid < 54){
        int u = tid / 9, b = tid % 9;
        float pre = stg[u*9+b] + stg[54 + u*9+b] + stg[108 + u*9+b] + stg[162 + u*9+b];
        float rel = fmaxf(pre, 0.f);
        float mn;
        if (s == 0) mn = rel;
        else {
          float mp = mst[b*6 + u];
          mn = 0.2f*rel + 0.8f*mp + nz*mp*mp;
        }
        mst[b*6 + u] = mn;
      }
      __syncthreads();
      if (s == 0){
        if (tid < 18){
          int b = tid >> 1, c = tid & 1;
          js[b*4 + c] = hoL[b*2 + c];
          js[b*4 + 2 + c] = 0.f;
          out[b*4 + c] = hoL[b*2 + c];
          out[b*4 + 2 + c] = 0.f;
        }
      } else {
        if (tid < 18){
          int b = tid >> 1, c = tid & 1;
          float tq = 0.f;
          #pragma unroll
          for (int u = 0; u < 6; ++u) tq = fmaf(mst[b*6 + u], MaL[u*2 + c], tq);
          tq += pv;
          float v  = js[b*4 + 2 + c] + 0.01f * tq;
          float pn = js[b*4 + c] + 0.01f * v;
          js[b*4 + c] = pn;
          js[b*4 + 2 + c] = v;
          out[(size_t)s*(BB*4) + b*4 + c]     = pn;
          out[(size_t)s*(BB*4) + b*4 + 2 + c] = v;
        }
      }
      __syncthreads();
      if (tid < BB*12){
        int b = tid / 12, k = tid % 12;
        float val;
        if (k < 2)       val = 2.f * (js[b*4 + k] - hoL[b*2 + k]);
        else if (k < 4)  val = 0.5f * js[b*4 + 2 + (k - 2)];
        else if (k < 10) val = mst[b*6 + (k - 4)];
        else             val = 0.f;
        if (s == 0){
          #pragma unroll
          for (int q = 1; q <= 6; ++q) RIV[q*(BB*12) + tid] = val;
        } else {
          RIV[((s + 6) & (IVR-1))*(BB*12) + tid] = val;
        }
      }
      asm volatile("s_waitcnt vmcnt(0)" ::: "memory");
      __syncthreads();
      if (tid == 0)
        __hip_atomic_fetch_add(myF, 1, __ATOMIC_RELAXED, __HIP_MEMORY_SCOPE_AGENT);
    }
  }
}

extern "C" void kernel_launch(void* const* d_in, const int* in_sizes, int n_in,
                              void* d_out, int out_size, void* d_ws, size_t ws_size,
                              hipStream_t stream) {
  const float* pert = (const float*)d_in[1];
  const float* n1   = (const float*)d_in[2];
  const float* n2   = (const float*)d_in[3];
  const float* nm   = (const float*)d_in[4];
  const float* home = (const float*)d_in[5];
  const float* Win  = (const float*)d_in[6];
  const float* bin  = (const float*)d_in[7];
  const float* Wis  = (const float*)d_in[8];
  const float* Wo   = (const float*)d_in[9];
  const float* bout = (const float*)d_in[10];
  const float* Wos  = (const float*)d_in[11];
  const float* Wmus = (const float*)d_in[12];
  const float* Marm = (const float*)d_in[13];
  (void)in_sizes; (void)n_in; (void)out_size; (void)ws_size; // needs ~318 KB ws

  // reset flags + ticket every launch (flags only ever written at MALL)
  (void)hipMemsetAsync(d_ws, 0, 16384, stream);
  // fill the whole chip so every CU gets one block; workers self-select on XCD0
  hipLaunchKernelGGL(fb_pipe, dim3(256), dim3(256), 0, stream,
                     pert, n1, n2, nm, home, Win, bin, Wis, Wo, bout, Wos,
                     Wmus, Marm, (float*)d_out, (float*)d_ws);
}

// Round 15
// 25883.759 us; speedup vs baseline: 1.0190x; 1.0032x over previous
//
#include <hip/hip_runtime.h>
#include <math.h>

// ---------------- problem constants ----------------
#define TT   4096
#define BB   9
#define NHc  500
#define NHP  512
#define NMc  6
// ---------------- grid roles (workers live on ONE XCD) ----------------
#define NAg  8      // A: 64 h1 rows each, W_in_self in REGISTERS
#define NBg  16     // B: 32 h2 rows each, W_out + W_out_self in REGISTERS
#define NWRK (NAg + NBg + 1)
#define RGD  8      // h ring depth
#define IVR  16     // in_vec ring depth

// ws ints: FA[i]=32*i (i<8); FB[j]=1024+32*j (j<16); FC=3040; TICKET=3104.
#define WS_RH1 4096
#define WS_RH2 (WS_RH1 + RGD*BB*NHP)     // 40960
#define WS_RIV (WS_RH2 + RGD*BB*NHP)     // 77824 (+16*108 -> ~318KB)

// PROVEN transport (R1/R6/R8/R9/R12 pass; R2/R3/R4/R5/R10/R13 falsified):
//  - flags: publish = agent-scope atomic fetch_add (MALL RMW);
//           poll    = relaxed agent-scope atomic load + s_sleep backoff.
//  - ring data (XCD-local): plain stores -> per-thread s_waitcnt vmcnt(0) ->
//    barrier -> flag RMW; consumers read with sc0 (L1-bypass) loads served
//    by the shared per-XCD L2. No fences, no MALL round trips for data.
__device__ __forceinline__ bool waitFlag(const int* p, int tgt){
  if (tgt <= 0) return true;
  long long n = 0;
  while (__hip_atomic_load(p, __ATOMIC_RELAXED, __HIP_MEMORY_SCOPE_AGENT) < tgt){
    __builtin_amdgcn_s_sleep(2);
    if (++n > (1LL<<20)) return false;   // safety: wrong answer instead of hang
  }
  return true;
}
// ring slice (BB*NHP floats = 2304 u64) -> LDS, sc0 = bypass L1, hit shared L2
__device__ __forceinline__ void fetchSlice(float* dstLds, const float* src, int tid){
  const unsigned long long* s64 = (const unsigned long long*)src;
  unsigned long long v0,v1,v2,v3,v4,v5,v6,v7,v8;
  asm volatile("global_load_dwordx2 %0, %1, off sc0" : "=v"(v0) : "v"(&s64[tid        ]));
  asm volatile("global_load_dwordx2 %0, %1, off sc0" : "=v"(v1) : "v"(&s64[tid +  256]));
  asm volatile("global_load_dwordx2 %0, %1, off sc0" : "=v"(v2) : "v"(&s64[tid +  512]));
  asm volatile("global_load_dwordx2 %0, %1, off sc0" : "=v"(v3) : "v"(&s64[tid +  768]));
  asm volatile("global_load_dwordx2 %0, %1, off sc0" : "=v"(v4) : "v"(&s64[tid + 1024]));
  asm volatile("global_load_dwordx2 %0, %1, off sc0" : "=v"(v5) : "v"(&s64[tid + 1280]));
  asm volatile("global_load_dwordx2 %0, %1, off sc0" : "=v"(v6) : "v"(&s64[tid + 1536]));
  asm volatile("global_load_dwordx2 %0, %1, off sc0" : "=v"(v7) : "v"(&s64[tid + 1792]));
  asm volatile("global_load_dwordx2 %0, %1, off sc0" : "=v"(v8) : "v"(&s64[tid + 2048]));
  asm volatile("s_waitcnt vmcnt(0)" ::: "memory");
  __builtin_amdgcn_sched_barrier(0);
  unsigned long long* d64 = (unsigned long long*)dstLds;
  d64[tid       ] = v0; d64[tid +  256] = v1; d64[tid +  512] = v2;
  d64[tid +  768] = v3; d64[tid + 1024] = v4; d64[tid + 1280] = v5;
  d64[tid + 1536] = v6; d64[tid + 1792] = v7; d64[tid + 2048] = v8;
}
__device__ __forceinline__ unsigned long long ld2sc0(const float* src){
  unsigned long long v;
  asm volatile("global_load_dwordx2 %0, %1, off sc0\n\ts_waitcnt vmcnt(0)"
               : "=v"(v) : "v"(src) : "memory");
  return v;
}

extern "C" __global__ void __launch_bounds__(256, 1)
fb_pipe(const float* __restrict__ pert,
        const float* __restrict__ n1g, const float* __restrict__ n2g,
        const float* __restrict__ nmg, const float* __restrict__ homeg,
        const float* __restrict__ Win,  const float* __restrict__ binp,
        const float* __restrict__ Wis,  const float* __restrict__ Wo,
        const float* __restrict__ boutp,const float* __restrict__ Wos,
        const float* __restrict__ Wmus, const float* __restrict__ Marm,
        float* __restrict__ out, float* ws)
{
  __shared__ float sm[8192];           // 32 KB, role-specific layout
  __shared__ unsigned smDead;
  __shared__ int smRank;
  int* FLG = (int*)ws;
  float* RH1 = ws + WS_RH1;
  float* RH2 = ws + WS_RH2;
  float* RIV = ws + WS_RIV;

  const int tid = threadIdx.x;
  const int wave = tid >> 6, lane = tid & 63;
  const int kk = lane & 15, rr = lane >> 4;

  // ---- claim a worker slot iff this block landed on XCD 0 ----
  if (tid == 0){
    unsigned xcc;
    asm volatile("s_getreg_b32 %0, hwreg(HW_REG_XCC_ID)" : "=s"(xcc));
    int r = -1;
    if (xcc == 0)
      r = __hip_atomic_fetch_add(&FLG[3104], 1, __ATOMIC_RELAXED, __HIP_MEMORY_SCOPE_AGENT);
    smRank = r;
    smDead = 0u;
  }
  __syncthreads();
  const int rank = smRank;
  if (rank < 0 || rank >= NWRK) return;

  if (rank < NAg) {
    // ======== stage A : h1 rows [rank*64, +64), weights in registers ========
    float* Xh   = sm;            // [BB][NHP]
    float* ivl  = sm + 4608;     // [BB][12]
    float* WinL = sm + 4716;     // [64][12]
    float* binL = sm + 5484;     // [64]
    float* stg  = sm + 5548;     // [64][9]
    const int rowBase = rank * 64;
    int* myF = &FLG[rank*32];
    const int wr = wave*16 + rr*4;       // 4 rows per thread
    float4 wreg[4][8];
    for (int q = 0; q < 4; ++q){
      int gr = rowBase + wr + q;
      for (int it = 0; it < 8; ++it){
        int jb = it*64 + kk*4;
        float4 v = {0.f,0.f,0.f,0.f};
        if (gr < NHc && jb < NHc) v = *(const float4*)&Wis[gr*NHc + jb];
        wreg[q][it] = v;
      }
    }
    for (int i = tid; i < 64*12; i += 256){
      int r = i/12, c = i%12; int gr = rowBase + r;
      WinL[i] = (gr < NHc) ? Win[gr*12 + c] : 0.f;
    }
    if (tid < 64){ int gr = rowBase + tid; binL[tid] = (gr < NHc) ? binp[gr] : 0.f; }
    __syncthreads();

    for (int s = 0; s < TT; ++s){
      float nz0=0.f, nz1=0.f, nz2=0.f;
      if (s > 0){
        { int i=tid,     b=i>>6, r=i&63, gr=rowBase+r; if (gr<NHc) nz0=n1g[(size_t)(s-1)*4500 + b*500 + gr]; }
        { int i=tid+256, b=i>>6, r=i&63, gr=rowBase+r; if (gr<NHc) nz1=n1g[(size_t)(s-1)*4500 + b*500 + gr]; }
        if (tid < 64){ int i=tid+512, b=i>>6, r=i&63, gr=rowBase+r; if (gr<NHc) nz2=n1g[(size_t)(s-1)*4500 + b*500 + gr]; }
      }
      // polls: wave0 = read gates (A peers + C in_vec); wave1 = B backpressure
      if (!smDead){
        bool ok = true;
        if (wave == 0){
          if (lane < NAg)        ok = waitFlag(&FLG[lane*32], s);
          else if (lane == 10){ int t=(s==0)?0:((s<=6)?1:(s-5)); ok = waitFlag(&FLG[3040], t); }
        } else if (wave == 1 && lane < NBg){
          if (s >= RGD) ok = waitFlag(&FLG[1024 + lane*32], s - (RGD-1));
        }
        if (!ok) smDead = 1u;
      }
      __syncthreads();
      if (s == 0){
        for (int i = tid; i < BB*NHP; i += 256) Xh[i] = 0.f;
        if (tid < 108) ivl[tid] = 0.f;
      } else {
        fetchSlice(Xh, RH1 + ((s-1)&7)*4608, tid);
        if (tid < 54){
          int b = tid/6, k0 = (tid%6)*2;
          unsigned long long v = ld2sc0(RIV + (s&15)*108 + b*12 + k0);
          *(unsigned long long*)&ivl[b*12 + k0] = v;
        }
      }
      __syncthreads();

      float acc[4][9];
      for (int q = 0; q < 4; ++q)
        for (int b = 0; b < 9; ++b) acc[q][b] = 0.f;
      #pragma unroll
      for (int it = 0; it < 8; ++it){
        int jb = it*64 + kk*4;
        #pragma unroll
        for (int b = 0; b < 9; ++b){
          float4 h = *(const float4*)&Xh[b*NHP + jb];
          #pragma unroll
          for (int q = 0; q < 4; ++q)
            acc[q][b] = fmaf(wreg[q][it].x,h.x, fmaf(wreg[q][it].y,h.y,
                        fmaf(wreg[q][it].z,h.z, fmaf(wreg[q][it].w,h.w, acc[q][b]))));
        }
      }
      #pragma unroll
      for (int mk = 1; mk < 16; mk <<= 1)
        #pragma unroll
        for (int q = 0; q < 4; ++q)
          #pragma unroll
          for (int b = 0; b < 9; ++b)
            acc[q][b] += __shfl_xor(acc[q][b], mk, 64);
      if (kk < 9){
        #pragma unroll
        for (int q = 0; q < 4; ++q){
          float v = 0.f;
          #pragma unroll
          for (int b = 0; b < 9; ++b){ if (kk == b) v = acc[q][b]; }
          stg[(wr+q)*9 + kk] = v;
        }
      }
      __syncthreads();

      const int fr = tid / 9, fb = tid % 9; (void)fr; (void)fb;
      #pragma unroll
      for (int c = 0; c < 3; ++c){
        int i = tid + c*256;
        if (i < 576){
          int b = i>>6, r = i&63, gr = rowBase + r;
          float h = 0.f;
          if (gr < NHc){
            float pre = stg[r*9 + b] + binL[r];
            #pragma unroll
            for (int cc = 0; cc < 10; ++cc) pre = fmaf(ivl[b*12 + cc], WinL[r*12 + 2 + cc], pre);
            if (s == 0) h = tanhf(pre);
            else {
              float hp = Xh[b*NHP + gr];
              float nz = (c==0)?nz0:((c==1)?nz1:nz2);
              h = 0.5f*tanhf(pre) + 0.5f*hp + nz*hp*hp;
            }
          }
          RH1[(s&7)*4608 + b*NHP + gr] = h;     // plain store -> shared L2
        }
      }
      asm volatile("s_waitcnt vmcnt(0)" ::: "memory");
      __syncthreads();
      if (tid == 0)
        __hip_atomic_fetch_add(myF, 1, __ATOMIC_RELAXED, __HIP_MEMORY_SCOPE_AGENT);
    }
  } else if (rank < NAg + NBg) {
    // ======== stage B : h2 rows [(rank-8)*32, +32), both weights in regs ========
    float* Xh  = sm;             // [BB][NHP] (reused: h2_{s-1} then h1_s)
    float* sv  = sm + 4608;      // [288]
    float* stg = sm + 4896;      // [32][9]
    float* boL = sm + 5184;      // [32]
    const int rowBase = (rank - NAg) * 32;
    int* myF = &FLG[1024 + (rank - NAg)*32];
    const int wr = wave*8 + rr*2;        // 2 rows per thread
    float4 wS[2][8], wO[2][8];
    for (int q = 0; q < 2; ++q){
      int gr = rowBase + wr + q;
      for (int it = 0; it < 8; ++it){
        int jb = it*64 + kk*4;
        float4 vs = {0.f,0.f,0.f,0.f}, vo = vs;
        if (gr < NHc && jb < NHc){
          vs = *(const float4*)&Wos[gr*NHc + jb];
          vo = *(const float4*)&Wo [gr*NHc + jb];
        }
        wS[q][it] = vs; wO[q][it] = vo;
      }
    }
    if (tid < 32){ int gr = rowBase + tid; boL[tid] = (gr < NHc) ? boutp[gr] : 0.f; }
    __syncthreads();

    for (int s = 0; s < TT; ++s){
      float nz0=0.f, nz1=0.f;
      if (s > 0){
        { int i=tid, b=i>>5, r=i&31, gr=rowBase+r; if (gr<NHc) nz0=n2g[(size_t)(s-1)*4500 + b*500 + gr]; }
        if (tid < 32){ int r=tid, gr=rowBase+r; if (gr<NHc) nz1=n2g[(size_t)(s-1)*4500 + 8*500 + gr]; }
      }
      // polls: B peers h2_{s-1}; A done step s (h1_s); C backpressure
      if (!smDead){
        bool ok = true;
        if (wave == 0){
          if (lane < NBg)        ok = waitFlag(&FLG[1024 + lane*32], s);
          else if (lane == 20){ if (s >= RGD) ok = waitFlag(&FLG[3040], s - (RGD-1)); }
        } else if (wave == 1 && lane < NAg){
          ok = waitFlag(&FLG[lane*32], s + 1);
        }
        if (!ok) smDead = 1u;
      }
      __syncthreads();
      if (s == 0){
        for (int i = tid; i < BB*NHP; i += 256) Xh[i] = 0.f;
      } else {
        fetchSlice(Xh, RH2 + ((s-1)&7)*4608, tid);
      }
      __syncthreads();
      { int i=tid, b=i>>5, r=i&31, gr=rowBase+r; sv[i] = (gr<NHc) ? Xh[b*NHP+gr] : 0.f; }
      if (tid < 32){ int r=tid, gr=rowBase+r; sv[tid+256] = (gr<NHc) ? Xh[8*NHP+gr] : 0.f; }

      float acc[2][9];
      for (int q = 0; q < 2; ++q)
        for (int b = 0; b < 9; ++b) acc[q][b] = 0.f;
      // self part: W_out_self @ h2_{s-1}
      #pragma unroll
      for (int it = 0; it < 8; ++it){
        int jb = it*64 + kk*4;
        #pragma unroll
        for (int b = 0; b < 9; ++b){
          float4 h = *(const float4*)&Xh[b*NHP + jb];
          #pragma unroll
          for (int q = 0; q < 2; ++q)
            acc[q][b] = fmaf(wS[q][it].x,h.x, fmaf(wS[q][it].y,h.y,
                        fmaf(wS[q][it].z,h.z, fmaf(wS[q][it].w,h.w, acc[q][b]))));
        }
      }
      __syncthreads();                   // done reading h2_{s-1}
      fetchSlice(Xh, RH1 + (s&7)*4608, tid);
      __syncthreads();
      // out part: W_out @ h1_s
      #pragma unroll
      for (int it = 0; it < 8; ++it){
        int jb = it*64 + kk*4;
        #pragma unroll
        for (int b = 0; b < 9; ++b){
          float4 h = *(const float4*)&Xh[b*NHP + jb];
          #pragma unroll
          for (int q = 0; q < 2; ++q)
            acc[q][b] = fmaf(wO[q][it].x,h.x, fmaf(wO[q][it].y,h.y,
                        fmaf(wO[q][it].z,h.z, fmaf(wO[q][it].w,h.w, acc[q][b]))));
        }
      }
      #pragma unroll
      for (int mk = 1; mk < 16; mk <<= 1)
        #pragma unroll
        for (int q = 0; q < 2; ++q)
          #pragma unroll
          for (int b = 0; b < 9; ++b)
            acc[q][b] += __shfl_xor(acc[q][b], mk, 64);
      if (kk < 9){
        #pragma unroll
        for (int q = 0; q < 2; ++q){
          float v = 0.f;
          #pragma unroll
          for (int b = 0; b < 9; ++b){ if (kk == b) v = acc[q][b]; }
          stg[(wr+q)*9 + kk] = v;
        }
      }
      __syncthreads();

      #pragma unroll
      for (int c = 0; c < 2; ++c){
        int i = tid + c*256;
        if (i < 288){
          int b = i>>5, r = i&31, gr = rowBase + r;
          float h = 0.f;
          if (gr < NHc){
            float pre = stg[r*9 + b] + boL[r];
            if (s == 0) h = tanhf(pre);
            else {
              float hp = sv[i];
              float nz = (c==0)?nz0:nz1;
              h = 0.5f*tanhf(pre) + 0.5f*hp + nz*hp*hp;
            }
          }
          RH2[(s&7)*4608 + b*NHP + gr] = h;     // plain store -> shared L2
        }
      }
      asm volatile("s_waitcnt vmcnt(0)" ::: "memory");
      __syncthreads();
      if (tid == 0)
        __hip_atomic_fetch_add(myF, 1, __ATOMIC_RELAXED, __HIP_MEMORY_SCOPE_AGENT);
    }
  } else {
    // ========== stage C : muscles + joints + output + in_vec (+6 ahead) ==========
    float* WmL  = sm;            // [6][516]
    float* Xh   = sm + 3096;     // [BB][NHP]
    float* stg  = sm + 7704;     // [4][6][9]
    float* mst  = sm + 7920;     // [BB][6]
    float* js   = sm + 7974;     // [BB][4]
    float* MaL  = sm + 8010;     // [6][2]
    float* hoL  = sm + 8022;     // [BB][2]
    int* myF = &FLG[3040];
    for (int i = tid; i < 6*512; i += 256){
      int r = i >> 9, j = i & 511;
      WmL[r*516 + j] = (j < NHc) ? Wmus[r*NHc + j] : 0.f;
    }
    if (tid < 12) MaL[tid] = Marm[tid];
    if (tid < 18) hoL[tid] = homeg[tid];
    __syncthreads();

    for (int s = 0; s < TT; ++s){
      float nz = 0.f, pv = 0.f;
      if (s > 0 && tid < 54){
        int u = tid / 9, b = tid % 9;
        nz = nmg[(size_t)(s-1)*(BB*NMc) + b*NMc + u];
      }
      if (s > 0 && tid < 18) pv = pert[(size_t)(s-1)*(BB*2) + tid];
      if (!smDead){
        bool ok = true;
        if (wave == 0 && lane < NBg) ok = waitFlag(&FLG[1024 + lane*32], s + 1);
        if (!ok) smDead = 1u;
      }
      __syncthreads();
      fetchSlice(Xh, RH2 + (s&7)*4608, tid);
      __syncthreads();
      {
        float a0[9], a1[9];
        for (int b = 0; b < 9; ++b){ a0[b] = 0.f; a1[b] = 0.f; }
        const int r0 = (rr < 3 ? rr : 0) * 2;
        #pragma unroll
        for (int it = 0; it < 2; ++it){
          int jb = wave*128 + it*64 + kk*4;
          float4 w0 = *(const float4*)&WmL[r0*516 + jb];
          float4 w1 = *(const float4*)&WmL[(r0+1)*516 + jb];
          #pragma unroll
          for (int b = 0; b < 9; ++b){
            float4 h = *(const float4*)&Xh[b*NHP + jb];
            a0[b] = fmaf(w0.x,h.x, fmaf(w0.y,h.y, fmaf(w0.z,h.z, fmaf(w0.w,h.w, a0[b]))));
            a1[b] = fmaf(w1.x,h.x, fmaf(w1.y,h.y, fmaf(w1.z,h.z, fmaf(w1.w,h.w, a1[b]))));
          }
        }
        #pragma unroll
        for (int mk = 1; mk < 16; mk <<= 1){
          #pragma unroll
          for (int b = 0; b < 9; ++b){
            a0[b] += __shfl_xor(a0[b], mk, 64);
            a1[b] += __shfl_xor(a1[b], mk, 64);
          }
        }
        if (kk < 9 && rr < 3){
          float v0 = 0.f, v1 = 0.f;
          #pragma unroll
          for (int b = 0; b < 9; ++b){ if (kk == b){ v0 = a0[b]; v1 = a1[b]; } }
          stg[wave*54 + (rr*2)*9   + kk] = v0;
          stg[wave*54 + (rr*2+1)*9 + kk] = v1;
        }
      }
      __syncthreads();
      if (tid < 54){
        int u = tid / 9, b = tid % 9;
        float pre = stg[u*9+b] + stg[54 + u*9+b] + stg[108 + u*9+b] + stg[162 + u*9+b];
        float rel = fmaxf(pre, 0.f);
        float mn;
        if (s == 0) mn = rel;
        else {
          float mp = mst[b*6 + u];
          mn = 0.2f*rel + 0.8f*mp + nz*mp*mp;
        }
        mst[b*6 + u] = mn;
      }
      __syncthreads();
      if (s == 0){
        if (tid < 18){
          int b = tid >> 1, c = tid & 1;
          js[b*4 + c] = hoL[b*2 + c];
          js[b*4 + 2 + c] = 0.f;
          out[b*4 + c] = hoL[b*2 + c];
          out[b*4 + 2 + c] = 0.f;
        }
      } else {
        if (tid < 18){
          int b = tid >> 1, c = tid & 1;
          float tq = 0.f;
          #pragma unroll
          for (int u = 0; u < 6; ++u) tq = fmaf(mst[b*6 + u], MaL[u*2 + c], tq);
          tq += pv;
          float v  = js[b*4 + 2 + c] + 0.01f * tq;
          float pn = js[b*4 + c] + 0.01f * v;
          js[b*4 + c] = pn;
          js[b*4 + 2 + c] = v;
          out[(size_t)s*(BB*4) + b*4 + c]     = pn;
          out[(size_t)s*(BB*4) + b*4 + 2 + c] = v;
        }
      }
      __syncthreads();
      if (tid < BB*12){
        int b = tid / 12, k = tid % 12;
        float val;
        if (k < 2)       val = 2.f * (js[b*4 + k] - hoL[b*2 + k]);
        else if (k < 4)  val = 0.5f * js[b*4 + 2 + (k - 2)];
        else if (k < 10) val = mst[b*6 + (k - 4)];
        else             val = 0.f;
        if (s == 0){
          #pragma unroll
          for (int q = 1; q <= 6; ++q) RIV[q*(BB*12) + tid] = val;
        } else {
          RIV[((s + 6) & (IVR-1))*(BB*12) + tid] = val;
        }
      }
      asm volatile("s_waitcnt vmcnt(0)" ::: "memory");
      __syncthreads();
      if (tid == 0)
        __hip_atomic_fetch_add(myF, 1, __ATOMIC_RELAXED, __HIP_MEMORY_SCOPE_AGENT);
    }
  }
}

extern "C" void kernel_launch(void* const* d_in, const int* in_sizes, int n_in,
                              void* d_out, int out_size, void* d_ws, size_t ws_size,
                              hipStream_t stream) {
  const float* pert = (const float*)d_in[1];
  const float* n1   = (const float*)d_in[2];
  const float* n2   = (const float*)d_in[3];
  const float* nm   = (const float*)d_in[4];
  const float* home = (const float*)d_in[5];
  const float* Win  = (const float*)d_in[6];
  const float* bin  = (const float*)d_in[7];
  const float* Wis  = (const float*)d_in[8];
  const float* Wo   = (const float*)d_in[9];
  const float* bout = (const float*)d_in[10];
  const float* Wos  = (const float*)d_in[11];
  const float* Wmus = (const float*)d_in[12];
  const float* Marm = (const float*)d_in[13];
  (void)in_sizes; (void)n_in; (void)out_size; (void)ws_size; // needs ~318 KB ws

  // reset flags + ticket every launch (flags only ever written at MALL)
  (void)hipMemsetAsync(d_ws, 0, 16384, stream);
  // fill the whole chip so every CU gets one block; workers self-select on XCD0
  hipLaunchKernelGGL(fb_pipe, dim3(256), dim3(256), 0, stream,
                     pert, n1, n2, nm, home, Win, bin, Wis, Wo, bout, Wos,
                     Wmus, Marm, (float*)d_out, (float*)d_ws);
}